// Round 6
// baseline (1283.900 us; speedup 1.0000x reference)
//
#include <hip/hip_runtime.h>
#include <math.h>

#define BB 32
#define TT 32
#define D_INX 128
#define NSLOT 512
#define MLEN 64
#define NREAD 4
#define NHEAD 5
#define CDIM 256
#define IDIM 478
#define RHL 70
#define NT 512          // threads per block (8 waves)

// d_ws: wctb bf16 [48 chunks][256 cols][8] = 196608 B @ 0
//       hkb  bf16 [32 chunks][478 cols][8] = 244736 B @ 196608
#define HKB_OFF 196608

struct SMem {
    float mem[NSLOT * MLEN];     // 131072 B — XOR-swizzled: logical f4 j of row n at n*16 + (j^(n&15))
    float wread4[NSLOT * 4];     //   8192 B — [n][4] read-head weights, b128 per row
    float wwrite[NSLOT];         //   2048 B — write-head weights
    float mn[NSLOT];             //   2048
    float ctrl[384];             //   1536  [x(128) | r(256)]
    float h[CDIM];               //   1024
    float instr[480];            //   1920
    float k[NHEAD * MLEN];       //   1280
    float e[MLEN];               //    256
    float a[MLEN];               //    256
    float u[2560];               //  10240  red(512) | rpart(2048)
};                               // 159872 B <= 163840

__device__ __forceinline__ unsigned short f2bf(float f) {
    unsigned u = __float_as_uint(f);
    return (unsigned short)((u + 0x7fffu + ((u >> 16) & 1u)) >> 16);
}

__global__ void pack_kernel(const float* __restrict__ Wc, const float* __restrict__ Hk,
                            unsigned short* __restrict__ wctb, unsigned short* __restrict__ hkb)
{
    int idx = blockIdx.x * 256 + threadIdx.x;
    if (idx < 384 * 256) {
        int i = idx >> 8, col = idx & 255;
        wctb[((i >> 3) * 256 + col) * 8 + (i & 7)] = f2bf(Wc[idx]);
    }
    if (idx < 256 * 478) {
        int i = idx / 478, col = idx - i * 478;
        hkb[((i >> 3) * 478 + col) * 8 + (i & 7)] = f2bf(Hk[idx]);
    }
}

// acc += (8 bf16 in wv) . (8 activations in cA,cB)
#define BF8_DOT4(wv, cA, cB, acc) do {                                          \
    unsigned _u0 = __float_as_uint((wv).x), _u1 = __float_as_uint((wv).y);      \
    unsigned _u2 = __float_as_uint((wv).z), _u3 = __float_as_uint((wv).w);      \
    acc += __uint_as_float(_u0 << 16) * (cA).x + __uint_as_float(_u0 & 0xffff0000u) * (cA).y; \
    acc += __uint_as_float(_u1 << 16) * (cA).z + __uint_as_float(_u1 & 0xffff0000u) * (cA).w; \
    acc += __uint_as_float(_u2 << 16) * (cB).x + __uint_as_float(_u2 & 0xffff0000u) * (cB).y; \
    acc += __uint_as_float(_u3 << 16) * (cB).z + __uint_as_float(_u3 & 0xffff0000u) * (cB).w; \
} while (0)

__global__ __launch_bounds__(NT, 2)
void ntm_kernel(const float* __restrict__ x,
                const float* __restrict__ bc,
                const float* __restrict__ hb,
                const unsigned short* __restrict__ wctb,
                const unsigned short* __restrict__ hkb,
                float* __restrict__ out)
{
    extern __shared__ float smem_f[];
    SMem* sc = (SMem*)smem_f;

    const int b    = blockIdx.x;
    const int tid  = threadIdx.x;
    const int lane = tid & 63;
    const int wave = tid >> 6;   // 0..7

    const float bcv = (tid < CDIM) ? bc[tid] : 0.f;
    const float hbv = (tid < IDIM) ? hb[tid] : 0.f;

    // ---- prologue ----
    {
        float4 z4 = make_float4(0.f, 0.f, 0.f, 0.f);
        float4* m4 = (float4*)sc->mem;
        for (int i = tid; i < NSLOT * MLEN / 4; i += NT) m4[i] = z4;
        ((float4*)sc->wread4)[tid] = z4;
        sc->wwrite[tid] = 0.f;
        sc->mn[tid] = 0.f;
        if (tid < 384) sc->ctrl[tid] = (tid < D_INX) ? x[(size_t)b * TT * D_INX + tid] : 0.f;
    }
    __syncthreads();

    for (int t = 0; t < TT; ++t) {
        // ---- P1a: GEMV1 K-split-2, bf16 weights, f4 activation broadcasts ----
        {
            int col = tid & 255, kb = tid >> 8;
            const float4* wq = (const float4*)wctb + kb * 24 * 256 + col;
            const float4* c4 = (const float4*)sc->ctrl + kb * 48;
            float acc = 0.f;
#pragma unroll
            for (int cc = 0; cc < 24; ++cc) {
                float4 wv = wq[cc * 256];
                float4 cA = c4[cc * 2], cB = c4[cc * 2 + 1];
                BF8_DOT4(wv, cA, cB, acc);
            }
            sc->u[kb * 256 + col] = acc;
        }
        // prefetch GEMV2 weights, batch A (in flight across B1/P1b/B2)
        float4 wA[16];
        if (tid < IDIM) {
            const float4* wq = (const float4*)hkb + tid;
#pragma unroll
            for (int c = 0; c < 16; ++c) wA[c] = wq[c * IDIM];
        }
        __syncthreads();                                   // B1

        // ---- P1b: combine + tanh -> h; stage x[t+1] ----
        if (tid < CDIM) {
            float v = bcv + sc->u[tid] + sc->u[256 + tid];
            float av = fabsf(v);
            float ex = __builtin_amdgcn_exp2f(av * 2.8853900817779268f);  // 2*log2(e)
            float r1 = 1.f - 2.f / (ex + 1.f);
            float hv = (v < 0.f) ? -r1 : r1;
            sc->h[tid] = hv;
            if (t == TT - 1) out[(size_t)b * CDIM + tid] = hv;
        } else if (tid < 384 && t + 1 < TT) {
            sc->ctrl[tid - 256] = x[((size_t)b * TT + t + 1) * D_INX + (tid - 256)];
        }
        if (t == TT - 1) break;
        __syncthreads();                                   // B2

        // ---- P2: GEMV2 (batch B loads first, then dot A, dot B) ----
        if (tid < IDIM) {
            const float4* wq = (const float4*)hkb + tid;
            float4 wB[16];
#pragma unroll
            for (int c = 0; c < 16; ++c) wB[c] = wq[(16 + c) * IDIM];
            const float4* h4 = (const float4*)sc->h;
            float acc = hbv;
#pragma unroll
            for (int c = 0; c < 16; ++c) {
                float4 cA = h4[c * 2], cB = h4[c * 2 + 1];
                BF8_DOT4(wA[c], cA, cB, acc);
            }
#pragma unroll
            for (int c = 0; c < 16; ++c) {
                float4 cA = h4[32 + c * 2], cB = h4[33 + c * 2];
                BF8_DOT4(wB[c], cA, cB, acc);
            }
            sc->instr[tid] = acc;
            if (tid < 350) {
                int hh = (tid * 937) >> 16;     // tid/70
                int m = tid - hh * RHL;
                if (m < MLEN) sc->k[hh * MLEN + m] = acc;
            } else if (tid < 414) {
                sc->e[tid - 350] = acc;
            } else {
                sc->a[tid - 414] = acc;
            }
        }
        __syncthreads();                                   // B3

        // ---- P3+P4 fused: wave = head; dots stay in registers ----
        if (wave < NHEAD) {
            const int h = wave;
            const float4* k4 = (const float4*)sc->k + h * 16;
            float4 kk[16];
#pragma unroll
            for (int q = 0; q < 16; ++q) kk[q] = k4[q];
            float sq = 0.f;
#pragma unroll
            for (int q = 0; q < 16; ++q)
                sq += kk[q].x * kk[q].x + kk[q].y * kk[q].y + kk[q].z * kk[q].z + kk[q].w * kk[q].w;
            float kn = sqrtf(sq);

            float dots[8], mnv[8];
#pragma unroll
            for (int j = 0; j < 8; ++j) {
                int n = j * 64 + lane, nx = n & 15;
                const float4* m4 = (const float4*)sc->mem + n * 16;
                float d = 0.f;
#pragma unroll
                for (int q = 0; q < 16; ++q) {
                    float4 mv = m4[q ^ nx];
                    d += mv.x * kk[q].x + mv.y * kk[q].y + mv.z * kk[q].z + mv.w * kk[q].w;
                }
                dots[j] = d;
                mnv[j] = sc->mn[n];
            }

            const float* ins = sc->instr + h * RHL;
            float beta = __expf(ins[64]);
            float g = 1.f / (1.f + __expf(-ins[65]));
            float v0 = ins[66], v1 = ins[67], v2 = ins[68];
            float mx3 = fmaxf(v0, fmaxf(v1, v2));
            float e0 = __expf(v0 - mx3), e1 = __expf(v1 - mx3), e2 = __expf(v2 - mx3);
            float inv3 = 1.f / (e0 + e1 + e2);
            float s0 = e0 * inv3, s1 = e1 * inv3, s2 = e2 * inv3;
            float tv = ins[69];
            float tp = fmaxf(tv, 0.f) + log1pf(__expf(-fabsf(tv))) + 1.f;

            float uu[8];
#pragma unroll
            for (int j = 0; j < 8; ++j)
                uu[j] = beta * dots[j] / (kn * mnv[j] + 1e-8f);

            float m = uu[0];
#pragma unroll
            for (int j = 1; j < 8; ++j) m = fmaxf(m, uu[j]);
#pragma unroll
            for (int off = 32; off; off >>= 1) m = fmaxf(m, __shfl_xor(m, off));
            float ev[8]; float Z = 0.f;
#pragma unroll
            for (int j = 0; j < 8; ++j) { ev[j] = __expf(uu[j] - m); Z += ev[j]; }
#pragma unroll
            for (int off = 32; off; off >>= 1) Z += __shfl_xor(Z, off);
            float invZ = 1.f / Z;

            float wg[8];
#pragma unroll
            for (int j = 0; j < 8; ++j) {
                int n = j * 64 + lane;
                float wp = (h < 4) ? sc->wread4[n * 4 + h] : sc->wwrite[n];
                wg[j] = g * ev[j] * invZ + (1.f - g) * wp;
            }
            int lm = (lane + 63) & 63, lp = (lane + 1) & 63;
            float rm[8], rp[8], b63[8], b0[8];
#pragma unroll
            for (int j = 0; j < 8; ++j) {
                rm[j]  = __shfl(wg[j], lm);
                rp[j]  = __shfl(wg[j], lp);
                b63[j] = __shfl(wg[j], 63);
                b0[j]  = __shfl(wg[j], 0);
            }
            if (lane == 0) {
#pragma unroll
                for (int j = 0; j < 8; ++j) rm[j] = b63[(j + 7) & 7];
            }
            if (lane == 63) {
#pragma unroll
                for (int j = 0; j < 8; ++j) rp[j] = b0[(j + 1) & 7];
            }
            float wt[8]; float S = 0.f;
#pragma unroll
            for (int j = 0; j < 8; ++j) {
                float wsh = s0 * rp[j] + s1 * wg[j] + s2 * rm[j];
                wt[j] = __builtin_amdgcn_exp2f(tp * __builtin_amdgcn_logf(wsh));
                S += wt[j];
            }
#pragma unroll
            for (int off = 32; off; off >>= 1) S += __shfl_xor(S, off);
            float invS = 1.f / (S + 1e-8f);
            if (h < 4) {
#pragma unroll
                for (int j = 0; j < 8; ++j)
                    sc->wread4[(j * 64 + lane) * 4 + h] = wt[j] * invS;
            } else {
#pragma unroll
                for (int j = 0; j < 8; ++j)
                    sc->wwrite[j * 64 + lane] = wt[j] * invS;
            }
        }
        __syncthreads();                                   // B4

        // ---- P5: erase/add update + row norm, thread = row ----
        {
            int n = tid, nx = n & 15;
            float4* m4 = (float4*)sc->mem + n * 16;
            const float4* e4 = (const float4*)sc->e;
            const float4* a4 = (const float4*)sc->a;
            float wv = sc->wwrite[n];
            float nsq = 0.f;
#pragma unroll
            for (int j = 0; j < 16; ++j) {
                float4 mv = m4[j ^ nx];
                float4 ev = e4[j], av = a4[j];
                mv.x = mv.x * (1.f - wv * ev.x) + wv * av.x;
                mv.y = mv.y * (1.f - wv * ev.y) + wv * av.y;
                mv.z = mv.z * (1.f - wv * ev.z) + wv * av.z;
                mv.w = mv.w * (1.f - wv * ev.w) + wv * av.w;
                nsq += mv.x * mv.x + mv.y * mv.y + mv.z * mv.z + mv.w * mv.w;
                m4[j ^ nx] = mv;
            }
            sc->mn[n] = sqrtf(nsq);
        }
        __syncthreads();                                   // B5

        // ---- P6: read pass, wread4 as b128 ----
        {
            int rg = lane >> 4, j = lane & 15;
            int base = wave * 64;
            float4 ac[4];
#pragma unroll
            for (int hh = 0; hh < 4; ++hh) ac[hh] = make_float4(0.f, 0.f, 0.f, 0.f);
#pragma unroll
            for (int i = 0; i < 16; ++i) {
                int n = base + 4 * i + rg;
                float4 mv = ((const float4*)sc->mem)[n * 16 + (j ^ (n & 15))];
                float4 wv = ((const float4*)sc->wread4)[n];
                ac[0].x += wv.x * mv.x; ac[0].y += wv.x * mv.y; ac[0].z += wv.x * mv.z; ac[0].w += wv.x * mv.w;
                ac[1].x += wv.y * mv.x; ac[1].y += wv.y * mv.y; ac[1].z += wv.y * mv.z; ac[1].w += wv.y * mv.w;
                ac[2].x += wv.z * mv.x; ac[2].y += wv.z * mv.y; ac[2].z += wv.z * mv.z; ac[2].w += wv.z * mv.w;
                ac[3].x += wv.w * mv.x; ac[3].y += wv.w * mv.y; ac[3].z += wv.w * mv.z; ac[3].w += wv.w * mv.w;
            }
            float* af = (float*)ac;
#pragma unroll
            for (int q = 0; q < 16; ++q) {
                af[q] += __shfl_xor(af[q], 16);
                af[q] += __shfl_xor(af[q], 32);
            }
            if (rg == 0) {
                float4* rp = (float4*)(sc->u + wave * 256);
                rp[0 * 16 + j] = ac[0];
                rp[1 * 16 + j] = ac[1];
                rp[2 * 16 + j] = ac[2];
                rp[3 * 16 + j] = ac[3];
            }
        }
        __syncthreads();                                   // B6

        // ---- P7: r-reduce into ctrl ----
        if (tid < 256) {
            float s = 0.f;
#pragma unroll
            for (int w = 0; w < 8; ++w) s += sc->u[w * 256 + tid];
            sc->ctrl[128 + tid] = s;
        }
        __syncthreads();                                   // B7
    }
}

extern "C" void kernel_launch(void* const* d_in, const int* in_sizes, int n_in,
                              void* d_out, int out_size, void* d_ws, size_t ws_size,
                              hipStream_t stream) {
    const float* x  = (const float*)d_in[0];
    const float* Wc = (const float*)d_in[1];
    const float* bc = (const float*)d_in[2];
    const float* Hk = (const float*)d_in[3];
    const float* hb = (const float*)d_in[4];
    float* out = (float*)d_out;

    unsigned short* wctb = (unsigned short*)d_ws;
    unsigned short* hkb  = (unsigned short*)((char*)d_ws + HKB_OFF);

    static_assert(sizeof(SMem) <= 163840, "LDS overflow");
    (void)hipFuncSetAttribute((const void*)ntm_kernel,
                              hipFuncAttributeMaxDynamicSharedMemorySize,
                              (int)sizeof(SMem));

    hipLaunchKernelGGL(pack_kernel, dim3(478), dim3(256), 0, stream, Wc, Hk, wctb, hkb);
    hipLaunchKernelGGL(ntm_kernel, dim3(BB), dim3(NT), sizeof(SMem), stream,
                       x, bc, hb, wctb, hkb, out);
}

// Round 7
// 965.685 us; speedup vs baseline: 1.3295x; 1.3295x over previous
//
#include <hip/hip_runtime.h>
#include <math.h>

#define BB 32
#define TT 32
#define D_INX 128
#define NSLOT 512
#define MLEN 64
#define NREAD 4
#define NHEAD 5
#define CDIM 256
#define IDIM 478
#define RHL 70
#define NT 512          // threads per block (8 waves)

// d_ws: wctb bf16 [48 chunks][256 cols][8] = 196608 B @ 0
//       hkb  bf16 [32 chunks][478 cols][8] = 244736 B @ 196608
#define HKB_OFF 196608

struct SMem {
    float mem[NSLOT * MLEN];     // 131072 B — swizzled: logical f4 j of row n at n*16 + (j^(n&15))
    float wread4[NSLOT * 4];     //   8192 B — [n][4] read-head weights (b128 per row)
    float wwrite[NSLOT];         //   2048 B
    float mn[NSLOT];             //   2048
    float ctrl[512];             //   2048  [x slot0(128) | x slot1(128) | r(256)]
    float h[CDIM];               //   1024
    float instr[480];            //   1920
    float k[NHEAD * MLEN];       //   1280
    float e[MLEN];               //    256
    float a[MLEN];               //    256
    float u[2560];               //  10240  wbuf(2560) | rpart(2048)
};                               // 160384 B <= 163840

__device__ __forceinline__ unsigned short f2bf(float f) {
    unsigned u = __float_as_uint(f);
    return (unsigned short)((u + 0x7fffu + ((u >> 16) & 1u)) >> 16);
}

__global__ void pack_kernel(const float* __restrict__ Wc, const float* __restrict__ Hk,
                            unsigned short* __restrict__ wctb, unsigned short* __restrict__ hkb)
{
    int idx = blockIdx.x * 256 + threadIdx.x;
    if (idx < 384 * 256) {
        int i = idx >> 8, col = idx & 255;
        wctb[((i >> 3) * 256 + col) * 8 + (i & 7)] = f2bf(Wc[idx]);
    }
    if (idx < 256 * 478) {
        int i = idx / 478, col = idx - i * 478;
        hkb[((i >> 3) * 478 + col) * 8 + (i & 7)] = f2bf(Hk[idx]);
    }
}

// acc += (8 bf16 in uint4 wv) . (8 fp32 activations in cA,cB)
#define BFU_DOT(wv, cA, cB, acc) do {                                           \
    unsigned _u0 = (wv).x, _u1 = (wv).y, _u2 = (wv).z, _u3 = (wv).w;            \
    acc += __uint_as_float(_u0 << 16) * (cA).x + __uint_as_float(_u0 & 0xffff0000u) * (cA).y; \
    acc += __uint_as_float(_u1 << 16) * (cA).z + __uint_as_float(_u1 & 0xffff0000u) * (cA).w; \
    acc += __uint_as_float(_u2 << 16) * (cB).x + __uint_as_float(_u2 & 0xffff0000u) * (cB).y; \
    acc += __uint_as_float(_u3 << 16) * (cB).z + __uint_as_float(_u3 & 0xffff0000u) * (cB).w; \
} while (0)

#define L2E 1.4426950408889634f
#define LN2 0.6931471805599453f

__global__ __launch_bounds__(NT, 2)
void ntm_kernel(const float* __restrict__ x,
                const float* __restrict__ bc,
                const float* __restrict__ hb,
                const unsigned short* __restrict__ wctb,
                const unsigned short* __restrict__ hkb,
                float* __restrict__ out)
{
    extern __shared__ float smem_f[];
    SMem* sc = (SMem*)smem_f;

    const int b    = blockIdx.x;
    const int tid  = threadIdx.x;
    const int lane = tid & 63;
    const int wave = tid >> 6;   // 0..7

    const float bcv = (tid < CDIM) ? bc[tid] : 0.f;
    const float hbv = (tid < IDIM) ? hb[tid] : 0.f;

    // ---- prologue ----
    {
        float4 z4 = make_float4(0.f, 0.f, 0.f, 0.f);
        float4* m4 = (float4*)sc->mem;
        for (int i = tid; i < NSLOT * MLEN / 4; i += NT) m4[i] = z4;
        ((float4*)sc->wread4)[tid] = z4;
        sc->wwrite[tid] = 0.f;
        sc->mn[tid] = 0.f;
        sc->ctrl[tid] = (tid < D_INX) ? x[(size_t)b * TT * D_INX + tid] : 0.f;
    }
    __syncthreads();

    for (int t = 0; t < TT; ++t) {
        // ---- P1: GEMV1 full-K (256 cols) + tanh; threads 256..287 stage x[t+1] ----
        if (tid < CDIM) {
            const uint4* wq = (const uint4*)wctb + tid;    // stride 256 per chunk
            const float4* xa = (const float4*)(sc->ctrl + ((t & 1) << 7));
            const float4* ra = (const float4*)(sc->ctrl + 256);
            float acc = bcv;
#pragma unroll
            for (int cc = 0; cc < 16; ++cc) {
                uint4 wv = wq[cc * 256];
                float4 cA = xa[2 * cc], cB = xa[2 * cc + 1];
                BFU_DOT(wv, cA, cB, acc);
            }
#pragma unroll
            for (int cc = 16; cc < 48; ++cc) {
                uint4 wv = wq[cc * 256];
                float4 cA = ra[2 * (cc - 16)], cB = ra[2 * (cc - 16) + 1];
                BFU_DOT(wv, cA, cB, acc);
            }
            // tanh(v) = sign(v) * (1 - 2/(exp2(2|v|*log2e)+1))
            float av = fabsf(acc);
            float ex = __builtin_amdgcn_exp2f(av * (2.f * L2E));
            float r1 = 1.f - 2.f / (ex + 1.f);
            float hv = (acc < 0.f) ? -r1 : r1;
            sc->h[tid] = hv;
            if (t == TT - 1) out[(size_t)b * CDIM + tid] = hv;
        } else if (tid < 288 && t + 1 < TT) {
            int i = tid - 256;
            ((float4*)(sc->ctrl + (((t + 1) & 1) << 7)))[i] =
                ((const float4*)(x + ((size_t)b * TT + t + 1) * D_INX))[i];
        }
        if (t == TT - 1) break;
        __syncthreads();                                   // B1

        // ---- P2: GEMV2 full-K (478 cols) -> instr; scatter k/e/a ----
        if (tid < IDIM) {
            const uint4* wq = (const uint4*)hkb + tid;     // stride IDIM per chunk
            const float4* h4 = (const float4*)sc->h;
            float acc = hbv;
#pragma unroll
            for (int c = 0; c < 32; ++c) {
                uint4 wv = wq[c * IDIM];
                float4 cA = h4[2 * c], cB = h4[2 * c + 1];
                BFU_DOT(wv, cA, cB, acc);
            }
            sc->instr[tid] = acc;
            if (tid < 350) {
                int hh = (tid * 937) >> 16;     // tid/70
                int m = tid - hh * RHL;
                if (m < MLEN) sc->k[hh * MLEN + m] = acc;
            } else if (tid < 414) {
                sc->e[tid - 350] = acc;
            } else {
                sc->a[tid - 414] = acc;
            }
        }
        __syncthreads();                                   // B2

        // ---- P3: sim dots, thread = row, swizzled f4 reads ----
        {
            int n = tid, nx = n & 15;
            const float4* m4 = (const float4*)sc->mem + n * 16;
            const float4* k4 = (const float4*)sc->k;
            float d0 = 0.f, d1 = 0.f, d2 = 0.f, d3 = 0.f, d4 = 0.f;
#pragma unroll
            for (int j = 0; j < 16; ++j) {
                float4 mv = m4[j ^ nx];
                float4 k0 = k4[j], k1 = k4[16 + j], k2 = k4[32 + j], k3 = k4[48 + j], kw = k4[64 + j];
                d0 += mv.x * k0.x + mv.y * k0.y + mv.z * k0.z + mv.w * k0.w;
                d1 += mv.x * k1.x + mv.y * k1.y + mv.z * k1.z + mv.w * k1.w;
                d2 += mv.x * k2.x + mv.y * k2.y + mv.z * k2.z + mv.w * k2.w;
                d3 += mv.x * k3.x + mv.y * k3.y + mv.z * k3.z + mv.w * k3.w;
                d4 += mv.x * kw.x + mv.y * kw.y + mv.z * kw.z + mv.w * kw.w;
            }
            sc->u[n] = d0; sc->u[512 + n] = d1; sc->u[1024 + n] = d2;
            sc->u[1536 + n] = d3; sc->u[2048 + n] = d4;
        }
        __syncthreads();                                   // B3

        // ---- P4: addressing, one wave per head ----
        if (wave < NHEAD) {
            const int h = wave;
            const float* ins = sc->instr + h * RHL;
            float kv = ins[lane];
            float sq = kv * kv;
#pragma unroll
            for (int off = 32; off; off >>= 1) sq += __shfl_xor(sq, off);
            float kn = sqrtf(sq);
            float beta = __expf(ins[64]);
            float g = 1.f / (1.f + __expf(-ins[65]));
            float v0 = ins[66], v1 = ins[67], v2 = ins[68];
            float mx3 = fmaxf(v0, fmaxf(v1, v2));
            float e0 = __expf(v0 - mx3), e1 = __expf(v1 - mx3), e2 = __expf(v2 - mx3);
            float inv3 = 1.f / (e0 + e1 + e2);
            float s0 = e0 * inv3, s1 = e1 * inv3, s2 = e2 * inv3;
            float tv = ins[69];
            // softplus(tv)+1 via exp2/log builtins
            float tp = fmaxf(tv, 0.f)
                     + LN2 * __builtin_amdgcn_logf(1.f + __builtin_amdgcn_exp2f(-fabsf(tv) * L2E))
                     + 1.f;

            float uu[8];
#pragma unroll
            for (int j = 0; j < 8; ++j) {
                int slot = j * 64 + lane;
                float d = sc->u[h * NSLOT + slot];
                uu[j] = beta * d / (kn * sc->mn[slot] + 1e-8f);
            }
            float m = uu[0];
#pragma unroll
            for (int j = 1; j < 8; ++j) m = fmaxf(m, uu[j]);
#pragma unroll
            for (int off = 32; off; off >>= 1) m = fmaxf(m, __shfl_xor(m, off));
            float ev[8]; float Z = 0.f;
#pragma unroll
            for (int j = 0; j < 8; ++j) { ev[j] = __expf(uu[j] - m); Z += ev[j]; }
#pragma unroll
            for (int off = 32; off; off >>= 1) Z += __shfl_xor(Z, off);
            float invZ = 1.f / Z;
            float wg[8];
#pragma unroll
            for (int j = 0; j < 8; ++j) {
                int n = j * 64 + lane;
                float wp = (h < 4) ? sc->wread4[n * 4 + h] : sc->wwrite[n];
                wg[j] = g * ev[j] * invZ + (1.f - g) * wp;
            }
            int lm = (lane + 63) & 63, lp = (lane + 1) & 63;
            float rm[8], rp[8], b63[8], b0[8];
#pragma unroll
            for (int j = 0; j < 8; ++j) {
                rm[j]  = __shfl(wg[j], lm);
                rp[j]  = __shfl(wg[j], lp);
                b63[j] = __shfl(wg[j], 63);
                b0[j]  = __shfl(wg[j], 0);
            }
            if (lane == 0) {
#pragma unroll
                for (int j = 0; j < 8; ++j) rm[j] = b63[(j + 7) & 7];
            }
            if (lane == 63) {
#pragma unroll
                for (int j = 0; j < 8; ++j) rp[j] = b0[(j + 1) & 7];
            }
            float wt[8]; float S = 0.f;
#pragma unroll
            for (int j = 0; j < 8; ++j) {
                float wsh = s0 * rp[j] + s1 * wg[j] + s2 * rm[j];
                wt[j] = __builtin_amdgcn_exp2f(tp * __builtin_amdgcn_logf(wsh));
                S += wt[j];
            }
#pragma unroll
            for (int off = 32; off; off >>= 1) S += __shfl_xor(S, off);
            float invS = 1.f / (S + 1e-8f);
            if (h < 4) {
#pragma unroll
                for (int j = 0; j < 8; ++j)
                    sc->wread4[(j * 64 + lane) * 4 + h] = wt[j] * invS;
            } else {
#pragma unroll
                for (int j = 0; j < 8; ++j)
                    sc->wwrite[j * 64 + lane] = wt[j] * invS;
            }
        }
        __syncthreads();                                   // B4

        // ---- P5: erase/add update + row norm, thread = row ----
        {
            int n = tid, nx = n & 15;
            float4* m4 = (float4*)sc->mem + n * 16;
            const float4* e4 = (const float4*)sc->e;
            const float4* a4 = (const float4*)sc->a;
            float wv = sc->wwrite[n];
            float nsq = 0.f;
#pragma unroll
            for (int j = 0; j < 16; ++j) {
                float4 mv = m4[j ^ nx];
                float4 ev = e4[j], av = a4[j];
                mv.x = mv.x * (1.f - wv * ev.x) + wv * av.x;
                mv.y = mv.y * (1.f - wv * ev.y) + wv * av.y;
                mv.z = mv.z * (1.f - wv * ev.z) + wv * av.z;
                mv.w = mv.w * (1.f - wv * ev.w) + wv * av.w;
                nsq += mv.x * mv.x + mv.y * mv.y + mv.z * mv.z + mv.w * mv.w;
                m4[j ^ nx] = mv;
            }
            sc->mn[n] = sqrtf(nsq);
        }
        __syncthreads();                                   // B5

        // ---- P6: read pass, wread4 + mem as b128 ----
        {
            int rg = lane >> 4, j = lane & 15;
            int base = wave * 64;
            float4 ac[4];
#pragma unroll
            for (int hh = 0; hh < 4; ++hh) ac[hh] = make_float4(0.f, 0.f, 0.f, 0.f);
#pragma unroll
            for (int i = 0; i < 16; ++i) {
                int n = base + 4 * i + rg;
                float4 mv = ((const float4*)sc->mem)[n * 16 + (j ^ (n & 15))];
                float4 wv = ((const float4*)sc->wread4)[n];
                ac[0].x += wv.x * mv.x; ac[0].y += wv.x * mv.y; ac[0].z += wv.x * mv.z; ac[0].w += wv.x * mv.w;
                ac[1].x += wv.y * mv.x; ac[1].y += wv.y * mv.y; ac[1].z += wv.y * mv.z; ac[1].w += wv.y * mv.w;
                ac[2].x += wv.z * mv.x; ac[2].y += wv.z * mv.y; ac[2].z += wv.z * mv.z; ac[2].w += wv.z * mv.w;
                ac[3].x += wv.w * mv.x; ac[3].y += wv.w * mv.y; ac[3].z += wv.w * mv.z; ac[3].w += wv.w * mv.w;
            }
            float* af = (float*)ac;
#pragma unroll
            for (int q = 0; q < 16; ++q) {
                af[q] += __shfl_xor(af[q], 16);
                af[q] += __shfl_xor(af[q], 32);
            }
            if (rg == 0) {
                float4* rp = (float4*)(sc->u + wave * 256);
                rp[0 * 16 + j] = ac[0];
                rp[1 * 16 + j] = ac[1];
                rp[2 * 16 + j] = ac[2];
                rp[3 * 16 + j] = ac[3];
            }
        }
        __syncthreads();                                   // B6

        // ---- P7: r-reduce into ctrl[256..511] ----
        if (tid < 256) {
            float s = 0.f;
#pragma unroll
            for (int w = 0; w < 8; ++w) s += sc->u[w * 256 + tid];
            sc->ctrl[256 + tid] = s;
        }
        __syncthreads();                                   // B7
    }
}

extern "C" void kernel_launch(void* const* d_in, const int* in_sizes, int n_in,
                              void* d_out, int out_size, void* d_ws, size_t ws_size,
                              hipStream_t stream) {
    const float* x  = (const float*)d_in[0];
    const float* Wc = (const float*)d_in[1];
    const float* bc = (const float*)d_in[2];
    const float* Hk = (const float*)d_in[3];
    const float* hb = (const float*)d_in[4];
    float* out = (float*)d_out;

    unsigned short* wctb = (unsigned short*)d_ws;
    unsigned short* hkb  = (unsigned short*)((char*)d_ws + HKB_OFF);

    static_assert(sizeof(SMem) <= 163840, "LDS overflow");
    (void)hipFuncSetAttribute((const void*)ntm_kernel,
                              hipFuncAttributeMaxDynamicSharedMemorySize,
                              (int)sizeof(SMem));

    hipLaunchKernelGGL(pack_kernel, dim3(478), dim3(256), 0, stream, Wc, Hk, wctb, hkb);
    hipLaunchKernelGGL(ntm_kernel, dim3(BB), dim3(NT), sizeof(SMem), stream,
                       x, bc, hb, wctb, hkb, out);
}

// Round 8
// 943.360 us; speedup vs baseline: 1.3610x; 1.0237x over previous
//
#include <hip/hip_runtime.h>
#include <math.h>

#define BB 32
#define TT 32
#define D_INX 128
#define NSLOT 512
#define MLEN 64
#define NREAD 4
#define NHEAD 5
#define CDIM 256
#define IDIM 478
#define RHL 70
#define NT 512          // threads per block (8 waves)

// d_ws: wctb bf16 [48 chunks][256 cols][8] = 196608 B @ 0
//       hkb  bf16 [32 chunks][478 cols][8] = 244736 B @ 196608
#define HKB_OFF 196608

struct SMem {
    float mem[NSLOT * MLEN];     // 131072 B — swizzled: logical f4 j of row n at n*16 + (j^(n&15))
    float wread4[NSLOT * 4];     //   8192 B — [n][4] read-head weights (b128 per row)
    float wwrite[NSLOT];         //   2048 B
    float mn[NSLOT];             //   2048
    float ctrl[512];             //   2048  [x slot0(128) | x slot1(128) | r(256)]
    float h[CDIM];               //   1024
    float instr[480];            //   1920
    float k[NHEAD * MLEN];       //   1280
    float e[MLEN];               //    256
    float a[MLEN];               //    256
    float xpart[CDIM];           //   1024  bc + x-part of GEMV1, computed a step ahead
    float u[2560];               //  10240  red(512) | wbuf(2560) | rpart(2048)
};                               // 161408 B <= 163840

__device__ __forceinline__ unsigned short f2bf(float f) {
    unsigned u = __float_as_uint(f);
    return (unsigned short)((u + 0x7fffu + ((u >> 16) & 1u)) >> 16);
}

__global__ void pack_kernel(const float* __restrict__ Wc, const float* __restrict__ Hk,
                            unsigned short* __restrict__ wctb, unsigned short* __restrict__ hkb)
{
    int idx = blockIdx.x * 256 + threadIdx.x;
    if (idx < 384 * 256) {
        int i = idx >> 8, col = idx & 255;
        wctb[((i >> 3) * 256 + col) * 8 + (i & 7)] = f2bf(Wc[idx]);
    }
    if (idx < 256 * 478) {
        int i = idx / 478, col = idx - i * 478;
        hkb[((i >> 3) * 478 + col) * 8 + (i & 7)] = f2bf(Hk[idx]);
    }
}

// acc += (8 bf16 in uint4 wv) . (8 fp32 activations in cA,cB)
#define BFU_DOT(wv, cA, cB, acc) do {                                           \
    unsigned _u0 = (wv).x, _u1 = (wv).y, _u2 = (wv).z, _u3 = (wv).w;            \
    acc += __uint_as_float(_u0 << 16) * (cA).x + __uint_as_float(_u0 & 0xffff0000u) * (cA).y; \
    acc += __uint_as_float(_u1 << 16) * (cA).z + __uint_as_float(_u1 & 0xffff0000u) * (cA).w; \
    acc += __uint_as_float(_u2 << 16) * (cB).x + __uint_as_float(_u2 & 0xffff0000u) * (cB).y; \
    acc += __uint_as_float(_u3 << 16) * (cB).z + __uint_as_float(_u3 & 0xffff0000u) * (cB).w; \
} while (0)

#define L2E 1.4426950408889634f
#define LN2 0.6931471805599453f

__global__ __launch_bounds__(NT, 2)
void ntm_kernel(const float* __restrict__ x,
                const float* __restrict__ bc,
                const float* __restrict__ hb,
                const unsigned short* __restrict__ wctb,
                const unsigned short* __restrict__ hkb,
                float* __restrict__ out)
{
    extern __shared__ float smem_f[];
    SMem* sc = (SMem*)smem_f;

    const int b    = blockIdx.x;
    const int tid  = threadIdx.x;
    const int lane = tid & 63;
    const int wave = tid >> 6;   // 0..7

    const float hbv = (tid < IDIM) ? hb[tid] : 0.f;

    // ---- prologue: zero state, stage x[0], compute xpart for t=0 ----
    {
        float4 z4 = make_float4(0.f, 0.f, 0.f, 0.f);
        float4* m4 = (float4*)sc->mem;
        for (int i = tid; i < NSLOT * MLEN / 4; i += NT) m4[i] = z4;
        ((float4*)sc->wread4)[tid] = z4;
        sc->wwrite[tid] = 0.f;
        sc->mn[tid] = 0.f;
        sc->ctrl[tid] = (tid < D_INX) ? x[(size_t)b * TT * D_INX + tid] : 0.f; // slot0=x[0], slot1+r zero
    }
    __syncthreads();
    if (tid < CDIM) {
        const uint4* wq = (const uint4*)wctb + tid;
        const float4* xa = (const float4*)sc->ctrl;     // slot 0
        float acc = bc[tid];
#pragma unroll
        for (int cc = 0; cc < 16; ++cc) {
            uint4 wv = wq[cc * 256];
            BFU_DOT(wv, xa[2 * cc], xa[2 * cc + 1], acc);
        }
        sc->xpart[tid] = acc;
    }
    __syncthreads();

    for (int t = 0; t < TT; ++t) {
        // ---- P1a: GEMV1 r-part only, K-split-2 over all 512 threads ----
        {
            int col = tid & 255, kb = tid >> 8;
            const uint4* wq = (const uint4*)wctb + (16 + kb * 16) * 256 + col;
            const float4* ra = (const float4*)(sc->ctrl + 256) + kb * 32;
            float acc = 0.f;
#pragma unroll
            for (int cc = 0; cc < 16; ++cc) {
                uint4 wv = wq[cc * 256];
                BFU_DOT(wv, ra[2 * cc], ra[2 * cc + 1], acc);
            }
            sc->u[kb * 256 + col] = acc;
        }
        __syncthreads();                                   // B1

        // ---- P1b: combine + tanh -> h ----
        if (tid < CDIM) {
            float acc = sc->xpart[tid] + sc->u[tid] + sc->u[256 + tid];
            float av = fabsf(acc);
            float ex = __builtin_amdgcn_exp2f(av * (2.f * L2E));
            float r1 = 1.f - 2.f / (ex + 1.f);
            float hv = (acc < 0.f) ? -r1 : r1;
            sc->h[tid] = hv;
            if (t == TT - 1) out[(size_t)b * CDIM + tid] = hv;
        }
        if (t == TT - 1) break;
        __syncthreads();                                   // B2

        // ---- P2: GEMV2 full-K -> instr (scatter k/e/a); threads 480+ stage x[t+1] ----
        if (tid < IDIM) {
            const uint4* wq = (const uint4*)hkb + tid;     // stride IDIM per chunk
            const float4* h4 = (const float4*)sc->h;
            float acc = hbv;
#pragma unroll
            for (int c = 0; c < 32; ++c) {
                uint4 wv = wq[c * IDIM];
                BFU_DOT(wv, h4[2 * c], h4[2 * c + 1], acc);
            }
            sc->instr[tid] = acc;
            if (tid < 350) {
                int hh = (tid * 937) >> 16;     // tid/70
                int m = tid - hh * RHL;
                if (m < MLEN) sc->k[hh * MLEN + m] = acc;
            } else if (tid < 414) {
                sc->e[tid - 350] = acc;
            } else {
                sc->a[tid - 414] = acc;
            }
        } else if (tid >= 480) {
            int i = tid - 480;                              // 32 threads x float4 = 128 floats
            ((float4*)(sc->ctrl + (((t + 1) & 1) << 7)))[i] =
                ((const float4*)(x + ((size_t)b * TT + t + 1) * D_INX))[i];
        }
        __syncthreads();                                   // B3

        // ---- P3: sim dots, thread = row, swizzled f4 reads ----
        {
            int n = tid, nx = n & 15;
            const float4* m4 = (const float4*)sc->mem + n * 16;
            const float4* k4 = (const float4*)sc->k;
            float d0 = 0.f, d1 = 0.f, d2 = 0.f, d3 = 0.f, d4 = 0.f;
#pragma unroll
            for (int j = 0; j < 16; ++j) {
                float4 mv = m4[j ^ nx];
                float4 k0 = k4[j], k1 = k4[16 + j], k2 = k4[32 + j], k3 = k4[48 + j], kw = k4[64 + j];
                d0 += mv.x * k0.x + mv.y * k0.y + mv.z * k0.z + mv.w * k0.w;
                d1 += mv.x * k1.x + mv.y * k1.y + mv.z * k1.z + mv.w * k1.w;
                d2 += mv.x * k2.x + mv.y * k2.y + mv.z * k2.z + mv.w * k2.w;
                d3 += mv.x * k3.x + mv.y * k3.y + mv.z * k3.z + mv.w * k3.w;
                d4 += mv.x * kw.x + mv.y * kw.y + mv.z * kw.z + mv.w * kw.w;
            }
            sc->u[n] = d0; sc->u[512 + n] = d1; sc->u[1024 + n] = d2;
            sc->u[1536 + n] = d3; sc->u[2048 + n] = d4;
        }
        __syncthreads();                                   // B4

        // ---- P4: waves 0..4 = addressing per head; waves 5..7 = xpart for t+1 ----
        if (wave < NHEAD) {
            const int h = wave;
            const float* ins = sc->instr + h * RHL;
            float kv = ins[lane];
            float sq = kv * kv;
#pragma unroll
            for (int off = 32; off; off >>= 1) sq += __shfl_xor(sq, off);
            float kn = sqrtf(sq);
            float beta = __expf(ins[64]);
            float g = 1.f / (1.f + __expf(-ins[65]));
            float v0 = ins[66], v1 = ins[67], v2 = ins[68];
            float mx3 = fmaxf(v0, fmaxf(v1, v2));
            float e0 = __expf(v0 - mx3), e1 = __expf(v1 - mx3), e2 = __expf(v2 - mx3);
            float inv3 = 1.f / (e0 + e1 + e2);
            float s0 = e0 * inv3, s1 = e1 * inv3, s2 = e2 * inv3;
            float tv = ins[69];
            float tp = fmaxf(tv, 0.f)
                     + LN2 * __builtin_amdgcn_logf(1.f + __builtin_amdgcn_exp2f(-fabsf(tv) * L2E))
                     + 1.f;

            float uu[8];
#pragma unroll
            for (int j = 0; j < 8; ++j) {
                int slot = j * 64 + lane;
                float d = sc->u[h * NSLOT + slot];
                uu[j] = beta * d / (kn * sc->mn[slot] + 1e-8f);
            }
            float m = uu[0];
#pragma unroll
            for (int j = 1; j < 8; ++j) m = fmaxf(m, uu[j]);
#pragma unroll
            for (int off = 32; off; off >>= 1) m = fmaxf(m, __shfl_xor(m, off));
            float ev[8]; float Z = 0.f;
#pragma unroll
            for (int j = 0; j < 8; ++j) { ev[j] = __expf(uu[j] - m); Z += ev[j]; }
#pragma unroll
            for (int off = 32; off; off >>= 1) Z += __shfl_xor(Z, off);
            float invZ = 1.f / Z;
            float wg[8];
#pragma unroll
            for (int j = 0; j < 8; ++j) {
                int n = j * 64 + lane;
                float wp = (h < 4) ? sc->wread4[n * 4 + h] : sc->wwrite[n];
                wg[j] = g * ev[j] * invZ + (1.f - g) * wp;
            }
            int lm = (lane + 63) & 63, lp = (lane + 1) & 63;
            float rm[8], rp[8], b63[8], b0[8];
#pragma unroll
            for (int j = 0; j < 8; ++j) {
                rm[j]  = __shfl(wg[j], lm);
                rp[j]  = __shfl(wg[j], lp);
                b63[j] = __shfl(wg[j], 63);
                b0[j]  = __shfl(wg[j], 0);
            }
            if (lane == 0) {
#pragma unroll
                for (int j = 0; j < 8; ++j) rm[j] = b63[(j + 7) & 7];
            }
            if (lane == 63) {
#pragma unroll
                for (int j = 0; j < 8; ++j) rp[j] = b0[(j + 1) & 7];
            }
            float wt[8]; float S = 0.f;
#pragma unroll
            for (int j = 0; j < 8; ++j) {
                float wsh = s0 * rp[j] + s1 * wg[j] + s2 * rm[j];
                wt[j] = __builtin_amdgcn_exp2f(tp * __builtin_amdgcn_logf(wsh));
                S += wt[j];
            }
#pragma unroll
            for (int off = 32; off; off >>= 1) S += __shfl_xor(S, off);
            float invS = 1.f / (S + 1e-8f);
            if (h < 4) {
#pragma unroll
                for (int j = 0; j < 8; ++j)
                    sc->wread4[(j * 64 + lane) * 4 + h] = wt[j] * invS;
            } else {
#pragma unroll
                for (int j = 0; j < 8; ++j)
                    sc->wwrite[j * 64 + lane] = wt[j] * invS;
            }
        } else {
            // xpart(t+1) = bc + x[t+1] @ Wc[x-part]  (192 threads, 256 cols)
            int idx = tid - 320;                            // 0..191
            const float4* xa = (const float4*)(sc->ctrl + (((t + 1) & 1) << 7));
            {
                int col = idx;
                const uint4* wq = (const uint4*)wctb + col;
                float acc = bc[col];
#pragma unroll
                for (int cc = 0; cc < 16; ++cc) {
                    uint4 wv = wq[cc * 256];
                    BFU_DOT(wv, xa[2 * cc], xa[2 * cc + 1], acc);
                }
                sc->xpart[col] = acc;
            }
            if (idx < 64) {
                int col = idx + 192;
                const uint4* wq = (const uint4*)wctb + col;
                float acc = bc[col];
#pragma unroll
                for (int cc = 0; cc < 16; ++cc) {
                    uint4 wv = wq[cc * 256];
                    BFU_DOT(wv, xa[2 * cc], xa[2 * cc + 1], acc);
                }
                sc->xpart[col] = acc;
            }
        }
        __syncthreads();                                   // B5

        // ---- P5: erase/add update + row norm, thread = row ----
        {
            int n = tid, nx = n & 15;
            float4* m4 = (float4*)sc->mem + n * 16;
            const float4* e4 = (const float4*)sc->e;
            const float4* a4 = (const float4*)sc->a;
            float wv = sc->wwrite[n];
            float nsq = 0.f;
#pragma unroll
            for (int j = 0; j < 16; ++j) {
                float4 mv = m4[j ^ nx];
                float4 ev = e4[j], av = a4[j];
                mv.x = mv.x * (1.f - wv * ev.x) + wv * av.x;
                mv.y = mv.y * (1.f - wv * ev.y) + wv * av.y;
                mv.z = mv.z * (1.f - wv * ev.z) + wv * av.z;
                mv.w = mv.w * (1.f - wv * ev.w) + wv * av.w;
                nsq += mv.x * mv.x + mv.y * mv.y + mv.z * mv.z + mv.w * mv.w;
                m4[j ^ nx] = mv;
            }
            sc->mn[n] = sqrtf(nsq);
        }
        __syncthreads();                                   // B6

        // ---- P6: read pass, wread4 + mem as b128 ----
        {
            int rg = lane >> 4, j = lane & 15;
            int base = wave * 64;
            float4 ac[4];
#pragma unroll
            for (int hh = 0; hh < 4; ++hh) ac[hh] = make_float4(0.f, 0.f, 0.f, 0.f);
#pragma unroll
            for (int i = 0; i < 16; ++i) {
                int n = base + 4 * i + rg;
                float4 mv = ((const float4*)sc->mem)[n * 16 + (j ^ (n & 15))];
                float4 wv = ((const float4*)sc->wread4)[n];
                ac[0].x += wv.x * mv.x; ac[0].y += wv.x * mv.y; ac[0].z += wv.x * mv.z; ac[0].w += wv.x * mv.w;
                ac[1].x += wv.y * mv.x; ac[1].y += wv.y * mv.y; ac[1].z += wv.y * mv.z; ac[1].w += wv.y * mv.w;
                ac[2].x += wv.z * mv.x; ac[2].y += wv.z * mv.y; ac[2].z += wv.z * mv.z; ac[2].w += wv.z * mv.w;
                ac[3].x += wv.w * mv.x; ac[3].y += wv.w * mv.y; ac[3].z += wv.w * mv.z; ac[3].w += wv.w * mv.w;
            }
            float* af = (float*)ac;
#pragma unroll
            for (int q = 0; q < 16; ++q) {
                af[q] += __shfl_xor(af[q], 16);
                af[q] += __shfl_xor(af[q], 32);
            }
            if (rg == 0) {
                float4* rp = (float4*)(sc->u + wave * 256);
                rp[0 * 16 + j] = ac[0];
                rp[1 * 16 + j] = ac[1];
                rp[2 * 16 + j] = ac[2];
                rp[3 * 16 + j] = ac[3];
            }
        }
        __syncthreads();                                   // B7

        // ---- P7: r-reduce into ctrl[256..511] ----
        if (tid < 256) {
            float s = 0.f;
#pragma unroll
            for (int w = 0; w < 8; ++w) s += sc->u[w * 256 + tid];
            sc->ctrl[256 + tid] = s;
        }
        __syncthreads();                                   // B8
    }
}

extern "C" void kernel_launch(void* const* d_in, const int* in_sizes, int n_in,
                              void* d_out, int out_size, void* d_ws, size_t ws_size,
                              hipStream_t stream) {
    const float* x  = (const float*)d_in[0];
    const float* Wc = (const float*)d_in[1];
    const float* bc = (const float*)d_in[2];
    const float* Hk = (const float*)d_in[3];
    const float* hb = (const float*)d_in[4];
    float* out = (float*)d_out;

    unsigned short* wctb = (unsigned short*)d_ws;
    unsigned short* hkb  = (unsigned short*)((char*)d_ws + HKB_OFF);

    static_assert(sizeof(SMem) <= 163840, "LDS overflow");
    (void)hipFuncSetAttribute((const void*)ntm_kernel,
                              hipFuncAttributeMaxDynamicSharedMemorySize,
                              (int)sizeof(SMem));

    hipLaunchKernelGGL(pack_kernel, dim3(478), dim3(256), 0, stream, Wc, Hk, wctb, hkb);
    hipLaunchKernelGGL(ntm_kernel, dim3(BB), dim3(NT), sizeof(SMem), stream,
                       x, bc, hb, wctb, hkb, out);
}

// Round 9
// 923.296 us; speedup vs baseline: 1.3906x; 1.0217x over previous
//
#include <hip/hip_runtime.h>
#include <math.h>

#define BB 32
#define TT 32
#define D_INX 128
#define NSLOT 512
#define MLEN 64
#define NREAD 4
#define NHEAD 5
#define CDIM 256
#define IDIM 478
#define NT 1024         // 16 waves

// d_ws: wctb bf16 [48 chunks][256 cols][8] = 196608 B @ 0
//       hkb  bf16 [32 chunks][478 permuted cols][8] = 244736 B @ 196608
#define HKB_OFF 196608

// permuted instr layout: [k 5*64 | e 64 @320 | a 64 @384 | scalars 5*6 @448]
// scalar block per head: beta,g,s0,s1,s2,gamma

struct SMem {
    float mem[NSLOT * MLEN];     // 131072 — swizzled: f4 j of row n at n*16 + (j^(n&15))
    float wread4[NSLOT * 4];     //   8192 — [n][4] read-head weights
    float wwrite[NSLOT];         //   2048
    float mn[NSLOT];             //   2048
    float ctrl[512];             //   2048  [x slot0(128) | x slot1(128) | r(256)]
    float h[CDIM];               //   1024
    float instr[480];            //   1920  permuted layout (16B-aligned k/e/a)
    float xpart[CDIM];           //   1024
    float u[2560];               //  10240  gemv1 partials (1024) | sim dots (2560)
};                               // 159616 <= 163840

__device__ __forceinline__ unsigned short f2bf(float f) {
    unsigned u = __float_as_uint(f);
    return (unsigned short)((u + 0x7fffu + ((u >> 16) & 1u)) >> 16);
}

__device__ __forceinline__ int permcol(int c) {
    if (c < 280) { int h = c / 70, m = c - h * 70;
        return (m < 64) ? h * 64 + m : 448 + h * 6 + (m - 64); }
    if (c < 344) return 256 + (c - 280);
    if (c < 350) return 472 + (c - 344);
    if (c < 414) return 320 + (c - 350);
    return 384 + (c - 414);
}

__global__ void pack_kernel(const float* __restrict__ Wc, const float* __restrict__ Hk,
                            unsigned short* __restrict__ wctb, unsigned short* __restrict__ hkb)
{
    int idx = blockIdx.x * 256 + threadIdx.x;
    if (idx < 384 * 256) {
        int i = idx >> 8, col = idx & 255;
        wctb[((i >> 3) * 256 + col) * 8 + (i & 7)] = f2bf(Wc[idx]);
    }
    if (idx < 256 * 478) {
        int i = idx / 478, c = idx - i * 478;
        hkb[((i >> 3) * 478 + permcol(c)) * 8 + (i & 7)] = f2bf(Hk[idx]);
    }
}

// acc += (8 bf16 in uint4 wv) . (8 fp32 activations in cA,cB)
#define BFU_DOT(wv, cA, cB, acc) do {                                           \
    unsigned _u0 = (wv).x, _u1 = (wv).y, _u2 = (wv).z, _u3 = (wv).w;            \
    acc += __uint_as_float(_u0 << 16) * (cA).x + __uint_as_float(_u0 & 0xffff0000u) * (cA).y; \
    acc += __uint_as_float(_u1 << 16) * (cA).z + __uint_as_float(_u1 & 0xffff0000u) * (cA).w; \
    acc += __uint_as_float(_u2 << 16) * (cB).x + __uint_as_float(_u2 & 0xffff0000u) * (cB).y; \
    acc += __uint_as_float(_u3 << 16) * (cB).z + __uint_as_float(_u3 & 0xffff0000u) * (cB).w; \
} while (0)

#define L2E 1.4426950408889634f
#define LN2 0.6931471805599453f

__global__ __launch_bounds__(NT, 4)
void ntm_kernel(const float* __restrict__ x,
                const float* __restrict__ bc,
                const float* __restrict__ hb,
                const unsigned short* __restrict__ wctb,
                const unsigned short* __restrict__ hkb,
                float* __restrict__ out)
{
    extern __shared__ float smem_f[];
    SMem* sc = (SMem*)smem_f;

    const int b    = blockIdx.x;
    const int tid  = threadIdx.x;
    const int lane = tid & 63;
    const int wave = tid >> 6;   // 0..15

    // per-thread preloads
    float hbv = 0.f;             // hb[invperm(j)] for instr-init threads
    if (tid >= 256 && tid < 256 + IDIM) {
        int j = tid - 256, c;
        if (j < 320) { int h = j >> 6, m = j & 63; c = (h < 4) ? h * 70 + m : 280 + m; }
        else if (j < 384) c = 350 + (j - 320);
        else if (j < 448) c = 414 + (j - 384);
        else { int q = j - 448; int h = q / 6, i = q - h * 6;
               c = (h < 4) ? h * 70 + 64 + i : 344 + i; }
        hbv = hb[c];
    }
    float bcv1 = (tid < CDIM) ? bc[tid] : 0.f;                       // P1 prologue xpart
    float bcv4 = (tid >= 320 && tid < 576) ? bc[tid - 320] : 0.f;    // P4 xpart

    // ---- prologue: zero state, stage x[0] ----
    {
        float4 z4 = make_float4(0.f, 0.f, 0.f, 0.f);
        float4* m4 = (float4*)sc->mem;
        for (int i = tid; i < NSLOT * MLEN / 4; i += NT) m4[i] = z4;
        if (tid < NSLOT) {
            ((float4*)sc->wread4)[tid] = z4;
            sc->wwrite[tid] = 0.f;
            sc->mn[tid] = 0.f;
            sc->ctrl[tid] = (tid < D_INX) ? x[(size_t)b * TT * D_INX + tid] : 0.f;
        }
    }
    __syncthreads();
    if (tid < CDIM) {       // xpart for t=0
        const uint4* wq = (const uint4*)wctb + tid;
        const float4* xa = (const float4*)sc->ctrl;
        float acc = bcv1;
#pragma unroll
        for (int cc = 0; cc < 16; ++cc) {
            uint4 wv = wq[cc * 256];
            BFU_DOT(wv, xa[2 * cc], xa[2 * cc + 1], acc);
        }
        sc->xpart[tid] = acc;
    }
    __syncthreads();

    for (int t = 0; t < TT; ++t) {
        // ---- P1a: GEMV1 r-part, K-split-4 over 1024 threads ----
        {
            int col = tid & 255, kb = tid >> 8;
            const uint4* wq = (const uint4*)wctb + (16 + kb * 8) * 256 + col;
            const float4* ra = (const float4*)(sc->ctrl + 256) + kb * 16;
            float acc = 0.f;
#pragma unroll
            for (int cc = 0; cc < 8; ++cc) {
                uint4 wv = wq[cc * 256];
                BFU_DOT(wv, ra[2 * cc], ra[2 * cc + 1], acc);
            }
            sc->u[kb * 256 + col] = acc;
        }
        __syncthreads();                                   // B1

        // ---- P1b: combine + tanh -> h; threads 256.. re-init instr with bias ----
        if (tid < CDIM) {
            float acc = sc->xpart[tid] + sc->u[tid] + sc->u[256 + tid]
                      + sc->u[512 + tid] + sc->u[768 + tid];
            float av = fabsf(acc);
            float ex = __builtin_amdgcn_exp2f(av * (2.f * L2E));
            float r1 = 1.f - 2.f / (ex + 1.f);
            float hv = (acc < 0.f) ? -r1 : r1;
            sc->h[tid] = hv;
            if (t == TT - 1) out[(size_t)b * CDIM + tid] = hv;
        } else if (tid < 256 + IDIM) {
            sc->instr[tid - 256] = hbv;
        }
        if (t == TT - 1) break;
        __syncthreads();                                   // B2

        // ---- P2: GEMV2 K-split-2, atomic combine into instr; tail stages x[t+1] ----
        {
            int col = tid & 511, kb = tid >> 9;
            if (col < IDIM) {
                const uint4* wq = (const uint4*)hkb + kb * 16 * IDIM + col;
                const float4* h4 = (const float4*)sc->h + kb * 32;
                float acc = 0.f;
#pragma unroll
                for (int cc = 0; cc < 16; ++cc) {
                    uint4 wv = wq[cc * IDIM];
                    BFU_DOT(wv, h4[2 * cc], h4[2 * cc + 1], acc);
                }
                atomicAdd(&sc->instr[col], acc);
            } else if (tid >= 990 && tid < 1022) {
                int i = tid - 990;      // 32 threads x f4 = x[t+1]
                ((float4*)(sc->ctrl + (((t + 1) & 1) << 7)))[i] =
                    ((const float4*)(x + ((size_t)b * TT + t + 1) * D_INX))[i];
            }
        }
        __syncthreads();                                   // B3

        // ---- P3: sim dots, 2 threads/row ----
        {
            int n = tid >> 1, half = tid & 1, nx = n & 15;
            const float4* m4 = (const float4*)sc->mem + n * 16;
            const float4* kb4 = (const float4*)sc->instr;   // 5 heads x 16 f4
            float d0 = 0.f, d1 = 0.f, d2 = 0.f, d3 = 0.f, d4 = 0.f;
#pragma unroll
            for (int jj = 0; jj < 8; ++jj) {
                int j = half * 8 + jj;
                float4 mv = m4[j ^ nx];
                float4 k0 = kb4[j], k1 = kb4[16 + j], k2 = kb4[32 + j],
                       k3 = kb4[48 + j], kw = kb4[64 + j];
                d0 += mv.x * k0.x + mv.y * k0.y + mv.z * k0.z + mv.w * k0.w;
                d1 += mv.x * k1.x + mv.y * k1.y + mv.z * k1.z + mv.w * k1.w;
                d2 += mv.x * k2.x + mv.y * k2.y + mv.z * k2.z + mv.w * k2.w;
                d3 += mv.x * k3.x + mv.y * k3.y + mv.z * k3.z + mv.w * k3.w;
                d4 += mv.x * kw.x + mv.y * kw.y + mv.z * kw.z + mv.w * kw.w;
            }
            d0 += __shfl_xor(d0, 1); d1 += __shfl_xor(d1, 1); d2 += __shfl_xor(d2, 1);
            d3 += __shfl_xor(d3, 1); d4 += __shfl_xor(d4, 1);
            if (half == 0) {
                sc->u[n] = d0; sc->u[512 + n] = d1; sc->u[1024 + n] = d2;
                sc->u[1536 + n] = d3; sc->u[2048 + n] = d4;
            }
        }
        __syncthreads();                                   // B4

        // ---- P4: waves 0-4 addressing; waves 5-8 xpart(t+1); wave 9 zeroes r ----
        if (wave < NHEAD) {
            const int h = wave;
            const float* sb = sc->instr + 448 + h * 6;
            float kv = sc->instr[h * 64 + lane];
            float sq = kv * kv;
#pragma unroll
            for (int off = 32; off; off >>= 1) sq += __shfl_xor(sq, off);
            float kn = sqrtf(sq);
            float beta = __expf(sb[0]);
            float g = 1.f / (1.f + __expf(-sb[1]));
            float v0 = sb[2], v1 = sb[3], v2 = sb[4];
            float mx3 = fmaxf(v0, fmaxf(v1, v2));
            float e0 = __expf(v0 - mx3), e1 = __expf(v1 - mx3), e2 = __expf(v2 - mx3);
            float inv3 = 1.f / (e0 + e1 + e2);
            float s0 = e0 * inv3, s1 = e1 * inv3, s2 = e2 * inv3;
            float tv = sb[5];
            float tp = fmaxf(tv, 0.f)
                     + LN2 * __builtin_amdgcn_logf(1.f + __builtin_amdgcn_exp2f(-fabsf(tv) * L2E))
                     + 1.f;

            float uu[8];
#pragma unroll
            for (int j = 0; j < 8; ++j) {
                int slot = j * 64 + lane;
                float d = sc->u[h * NSLOT + slot];
                uu[j] = beta * d / (kn * sc->mn[slot] + 1e-8f);
            }
            float m = uu[0];
#pragma unroll
            for (int j = 1; j < 8; ++j) m = fmaxf(m, uu[j]);
#pragma unroll
            for (int off = 32; off; off >>= 1) m = fmaxf(m, __shfl_xor(m, off));
            float ev[8]; float Z = 0.f;
#pragma unroll
            for (int j = 0; j < 8; ++j) { ev[j] = __expf(uu[j] - m); Z += ev[j]; }
#pragma unroll
            for (int off = 32; off; off >>= 1) Z += __shfl_xor(Z, off);
            float invZ = 1.f / Z;
            float wg[8];
#pragma unroll
            for (int j = 0; j < 8; ++j) {
                int n = j * 64 + lane;
                float wp = (h < 4) ? sc->wread4[n * 4 + h] : sc->wwrite[n];
                wg[j] = g * ev[j] * invZ + (1.f - g) * wp;
            }
            int lm = (lane + 63) & 63, lp = (lane + 1) & 63;
            float rm[8], rp[8], b63[8], b0[8];
#pragma unroll
            for (int j = 0; j < 8; ++j) {
                rm[j]  = __shfl(wg[j], lm);
                rp[j]  = __shfl(wg[j], lp);
                b63[j] = __shfl(wg[j], 63);
                b0[j]  = __shfl(wg[j], 0);
            }
            if (lane == 0) {
#pragma unroll
                for (int j = 0; j < 8; ++j) rm[j] = b63[(j + 7) & 7];
            }
            if (lane == 63) {
#pragma unroll
                for (int j = 0; j < 8; ++j) rp[j] = b0[(j + 1) & 7];
            }
            float wt[8]; float S = 0.f;
#pragma unroll
            for (int j = 0; j < 8; ++j) {
                float wsh = s0 * rp[j] + s1 * wg[j] + s2 * rm[j];
                wt[j] = __builtin_amdgcn_exp2f(tp * __builtin_amdgcn_logf(wsh));
                S += wt[j];
            }
#pragma unroll
            for (int off = 32; off; off >>= 1) S += __shfl_xor(S, off);
            float invS = 1.f / (S + 1e-8f);
            if (h < 4) {
#pragma unroll
                for (int j = 0; j < 8; ++j)
                    sc->wread4[(j * 64 + lane) * 4 + h] = wt[j] * invS;
            } else {
#pragma unroll
                for (int j = 0; j < 8; ++j)
                    sc->wwrite[j * 64 + lane] = wt[j] * invS;
            }
        } else if (wave < 9) {
            int col = tid - 320;                            // 0..255
            const uint4* wq = (const uint4*)wctb + col;
            const float4* xa = (const float4*)(sc->ctrl + (((t + 1) & 1) << 7));
            float acc = bcv4;
#pragma unroll
            for (int cc = 0; cc < 16; ++cc) {
                uint4 wv = wq[cc * 256];
                BFU_DOT(wv, xa[2 * cc], xa[2 * cc + 1], acc);
            }
            sc->xpart[col] = acc;
        } else if (wave == 9) {
            ((float4*)(sc->ctrl + 256))[lane] = make_float4(0.f, 0.f, 0.f, 0.f);
        }
        __syncthreads();                                   // B5

        // ---- P5: erase/add + row norm, 2 threads/row ----
        {
            int n = tid >> 1, half = tid & 1, nx = n & 15;
            float4* m4 = (float4*)sc->mem + n * 16;
            const float4* e4 = (const float4*)(sc->instr + 320);
            const float4* a4 = (const float4*)(sc->instr + 384);
            float wv = sc->wwrite[n];
            float nsq = 0.f;
#pragma unroll
            for (int jj = 0; jj < 8; ++jj) {
                int j = half * 8 + jj;
                float4 mv = m4[j ^ nx];
                float4 ev = e4[j], av = a4[j];
                mv.x = mv.x * (1.f - wv * ev.x) + wv * av.x;
                mv.y = mv.y * (1.f - wv * ev.y) + wv * av.y;
                mv.z = mv.z * (1.f - wv * ev.z) + wv * av.z;
                mv.w = mv.w * (1.f - wv * ev.w) + wv * av.w;
                nsq += mv.x * mv.x + mv.y * mv.y + mv.z * mv.z + mv.w * mv.w;
                m4[j ^ nx] = mv;
            }
            nsq += __shfl_xor(nsq, 1);
            if (half == 0) sc->mn[n] = sqrtf(nsq);
        }
        __syncthreads();                                   // B6

        // ---- P6: read pass, 16 waves x 32 rows; ds_add into ctrl r-region ----
        {
            int rg = lane >> 4, j = lane & 15;
            int base = wave * 32;
            float4 ac0 = make_float4(0.f,0.f,0.f,0.f), ac1 = ac0, ac2 = ac0, ac3 = ac0;
#pragma unroll
            for (int i = 0; i < 8; ++i) {
                int n = base + 4 * i + rg;
                float4 mv = ((const float4*)sc->mem)[n * 16 + (j ^ (n & 15))];
                float4 wv = ((const float4*)sc->wread4)[n];
                ac0.x += wv.x * mv.x; ac0.y += wv.x * mv.y; ac0.z += wv.x * mv.z; ac0.w += wv.x * mv.w;
                ac1.x += wv.y * mv.x; ac1.y += wv.y * mv.y; ac1.z += wv.y * mv.z; ac1.w += wv.y * mv.w;
                ac2.x += wv.z * mv.x; ac2.y += wv.z * mv.y; ac2.z += wv.z * mv.z; ac2.w += wv.z * mv.w;
                ac3.x += wv.w * mv.x; ac3.y += wv.w * mv.y; ac3.z += wv.w * mv.z; ac3.w += wv.w * mv.w;
            }
            float af[16] = { ac0.x, ac0.y, ac0.z, ac0.w, ac1.x, ac1.y, ac1.z, ac1.w,
                             ac2.x, ac2.y, ac2.z, ac2.w, ac3.x, ac3.y, ac3.z, ac3.w };
#pragma unroll
            for (int q = 0; q < 16; ++q) {
                af[q] += __shfl_xor(af[q], 16);
                af[q] += __shfl_xor(af[q], 32);
            }
            // head = rg; select its 4 components
            float sx = (rg == 0) ? af[0] : (rg == 1) ? af[4] : (rg == 2) ? af[8]  : af[12];
            float sy = (rg == 0) ? af[1] : (rg == 1) ? af[5] : (rg == 2) ? af[9]  : af[13];
            float sz = (rg == 0) ? af[2] : (rg == 1) ? af[6] : (rg == 2) ? af[10] : af[14];
            float sw = (rg == 0) ? af[3] : (rg == 1) ? af[7] : (rg == 2) ? af[11] : af[15];
            float* rdst = sc->ctrl + 256 + rg * 64 + j * 4;
            atomicAdd(&rdst[0], sx);
            atomicAdd(&rdst[1], sy);
            atomicAdd(&rdst[2], sz);
            atomicAdd(&rdst[3], sw);
        }
        __syncthreads();                                   // B7
    }
}

extern "C" void kernel_launch(void* const* d_in, const int* in_sizes, int n_in,
                              void* d_out, int out_size, void* d_ws, size_t ws_size,
                              hipStream_t stream) {
    const float* x  = (const float*)d_in[0];
    const float* Wc = (const float*)d_in[1];
    const float* bc = (const float*)d_in[2];
    const float* Hk = (const float*)d_in[3];
    const float* hb = (const float*)d_in[4];
    float* out = (float*)d_out;

    unsigned short* wctb = (unsigned short*)d_ws;
    unsigned short* hkb  = (unsigned short*)((char*)d_ws + HKB_OFF);

    static_assert(sizeof(SMem) <= 163840, "LDS overflow");
    (void)hipFuncSetAttribute((const void*)ntm_kernel,
                              hipFuncAttributeMaxDynamicSharedMemorySize,
                              (int)sizeof(SMem));

    hipLaunchKernelGGL(pack_kernel, dim3(478), dim3(256), 0, stream, Wc, Hk, wctb, hkb);
    hipLaunchKernelGGL(ntm_kernel, dim3(BB), dim3(NT), sizeof(SMem), stream,
                       x, bc, hb, wctb, hkb, out);
}

// Round 10
// 918.739 us; speedup vs baseline: 1.3975x; 1.0050x over previous
//
#include <hip/hip_runtime.h>
#include <math.h>

#define BB 32
#define TT 32
#define D_INX 128
#define NSLOT 512
#define MLEN 64
#define NREAD 4
#define NHEAD 5
#define CDIM 256
#define IDIM 478
#define NT 1024         // 16 waves

// d_ws: wctb bf16 [48 chunks][256 cols][8] = 196608 B @ 0
//       hkb  bf16 [32 chunks][478 permuted cols][8] = 244736 B @ 196608
#define HKB_OFF 196608

// permuted instr layout: [k 5*64 | e 64 @320 | a 64 @384 | scalars 5*6 @448]

struct SMem {
    float mem[NSLOT * MLEN];     // 131072 — swizzled: f4 j of row n at n*16 + (j^(n&15))
    float wread4[NSLOT * 4];     //   8192
    float wwrite[NSLOT];         //   2048
    float mn[NSLOT];             //   2048
    float ctrl[512];             //   2048  [x slot0(128) | x slot1(128) | r(256)]
    float h[CDIM];               //   1024
    float instr[480];            //   1920
    float xpart[CDIM];           //   1024
    float u[2560];               //  10240  sim dots
};                               // 159616 <= 163840

__device__ __forceinline__ unsigned short f2bf(float f) {
    unsigned u = __float_as_uint(f);
    return (unsigned short)((u + 0x7fffu + ((u >> 16) & 1u)) >> 16);
}

__device__ __forceinline__ int permcol(int c) {
    if (c < 280) { int h = c / 70, m = c - h * 70;
        return (m < 64) ? h * 64 + m : 448 + h * 6 + (m - 64); }
    if (c < 344) return 256 + (c - 280);
    if (c < 350) return 472 + (c - 344);
    if (c < 414) return 320 + (c - 350);
    return 384 + (c - 414);
}

__global__ void pack_kernel(const float* __restrict__ Wc, const float* __restrict__ Hk,
                            unsigned short* __restrict__ wctb, unsigned short* __restrict__ hkb)
{
    int idx = blockIdx.x * 256 + threadIdx.x;
    if (idx < 384 * 256) {
        int i = idx >> 8, col = idx & 255;
        wctb[((i >> 3) * 256 + col) * 8 + (i & 7)] = f2bf(Wc[idx]);
    }
    if (idx < 256 * 478) {
        int i = idx / 478, c = idx - i * 478;
        hkb[((i >> 3) * 478 + permcol(c)) * 8 + (i & 7)] = f2bf(Hk[idx]);
    }
}

#define BFU_DOT(wv, cA, cB, acc) do {                                           \
    unsigned _u0 = (wv).x, _u1 = (wv).y, _u2 = (wv).z, _u3 = (wv).w;            \
    acc += __uint_as_float(_u0 << 16) * (cA).x + __uint_as_float(_u0 & 0xffff0000u) * (cA).y; \
    acc += __uint_as_float(_u1 << 16) * (cA).z + __uint_as_float(_u1 & 0xffff0000u) * (cA).w; \
    acc += __uint_as_float(_u2 << 16) * (cB).x + __uint_as_float(_u2 & 0xffff0000u) * (cB).y; \
    acc += __uint_as_float(_u3 << 16) * (cB).z + __uint_as_float(_u3 & 0xffff0000u) * (cB).w; \
} while (0)

#define L2E 1.4426950408889634f
#define LN2 0.6931471805599453f

__global__ __launch_bounds__(NT)
void ntm_kernel(const float* __restrict__ x,
                const float* __restrict__ bc,
                const float* __restrict__ hb,
                const unsigned short* __restrict__ wctb,
                const unsigned short* __restrict__ hkb,
                float* __restrict__ out)
{
    extern __shared__ float smem_f[];
    SMem* sc = (SMem*)smem_f;

    const int b    = blockIdx.x;
    const int tid  = threadIdx.x;
    const int lane = tid & 63;
    const int wave = tid >> 6;   // 0..15

    // P1 mapping: col1 = wave*16 + (lane&15), ks = lane>>4
    const int col1 = (wave << 4) | (lane & 15);
    const int ks   = lane >> 4;
    // P2 mapping: col2 = wave*32 + (lane&31), sl = lane>>5 (waves 0..14)
    const int col2 = (wave << 5) | (lane & 31);
    const int sl   = lane >> 5;

    const float bcv1 = bc[col1];
    float hbv = 0.f;
    if (wave < 15 && sl == 0 && col2 < IDIM) {
        int j = col2, c;
        if (j < 320) { int h = j >> 6, m = j & 63; c = (h < 4) ? h * 70 + m : 280 + m; }
        else if (j < 384) c = 350 + (j - 320);
        else if (j < 448) c = 414 + (j - 384);
        else { int q = j - 448; int h = q / 6, i = q - h * 6;
               c = (h < 4) ? h * 70 + 64 + i : 344 + i; }
        hbv = hb[c];
    }
    const float bcv4 = (tid >= 320 && tid < 576) ? bc[tid - 320] : 0.f;   // P4 xpart

    // ---- prologue: zero state, stage x[0] ----
    {
        float4 z4 = make_float4(0.f, 0.f, 0.f, 0.f);
        float4* m4 = (float4*)sc->mem;
        for (int i = tid; i < NSLOT * MLEN / 4; i += NT) m4[i] = z4;
        if (tid < NSLOT) {
            ((float4*)sc->wread4)[tid] = z4;
            sc->wwrite[tid] = 0.f;
            sc->mn[tid] = 0.f;
            sc->ctrl[tid] = (tid < D_INX) ? x[(size_t)b * TT * D_INX + tid] : 0.f;
        }
    }
    __syncthreads();
    if (tid < CDIM) {       // xpart for t=0
        const uint4* wq = (const uint4*)wctb + tid;
        const float4* xa = (const float4*)sc->ctrl;
        float acc = bc[tid];
#pragma unroll
        for (int cc = 0; cc < 16; ++cc) {
            uint4 wv = wq[cc * 256];
            BFU_DOT(wv, xa[2 * cc], xa[2 * cc + 1], acc);
        }
        sc->xpart[tid] = acc;
    }
    __syncthreads();

    for (int t = 0; t < TT; ++t) {
        // ---- P1: GEMV1 r-part, in-wave K-split-4, shfl combine + tanh -> h ----
        {
            const float4* rb = (const float4*)(sc->ctrl + 256);
            float acc = 0.f;
#pragma unroll
            for (int cc = 0; cc < 8; ++cc) {
                int ce = (cc + ks) & 7;                       // bank-staggered chunk order
                int ch = ks * 8 + ce;                         // r-chunk 0..31
                uint4 wv = ((const uint4*)wctb)[(16 + ch) * 256 + col1];
                BFU_DOT(wv, rb[2 * ch], rb[2 * ch + 1], acc);
            }
            acc += __shfl_xor(acc, 16);
            acc += __shfl_xor(acc, 32);
            if (lane < 16) {
                acc += sc->xpart[col1];
                float av = fabsf(acc);
                float ex = __builtin_amdgcn_exp2f(av * (2.f * L2E));
                float r1 = 1.f - 2.f / (ex + 1.f);
                float hv = (acc < 0.f) ? -r1 : r1;
                sc->h[col1] = hv;
                if (t == TT - 1) out[(size_t)b * CDIM + col1] = hv;
            }
        }
        if (t == TT - 1) break;
        __syncthreads();                                   // B1

        // ---- P2: GEMV2 in-wave K-split-2, shfl combine -> instr; wave 15 stages x ----
        if (wave < 15) {
            if (col2 < IDIM) {
                const uint4* wq = (const uint4*)hkb + sl * 16 * IDIM + col2;
                const float4* h4 = (const float4*)sc->h + sl * 32;
                float acc = 0.f;
#pragma unroll
                for (int cc = 0; cc < 16; ++cc) {
                    uint4 wv = wq[cc * IDIM];
                    BFU_DOT(wv, h4[2 * cc], h4[2 * cc + 1], acc);
                }
                acc += __shfl_xor(acc, 32);
                if (sl == 0) sc->instr[col2] = acc + hbv;
            }
        } else if (lane < 32) {
            ((float4*)(sc->ctrl + (((t + 1) & 1) << 7)))[lane] =
                ((const float4*)(x + ((size_t)b * TT + t + 1) * D_INX))[lane];
        }
        __syncthreads();                                   // B2

        // ---- P3: sim dots, 2 threads/row ----
        {
            int n = tid >> 1, half = tid & 1, nx = n & 15;
            const float4* m4 = (const float4*)sc->mem + n * 16;
            const float4* kb4 = (const float4*)sc->instr;
            float d0 = 0.f, d1 = 0.f, d2 = 0.f, d3 = 0.f, d4 = 0.f;
#pragma unroll
            for (int jj = 0; jj < 8; ++jj) {
                int j = half * 8 + jj;
                float4 mv = m4[j ^ nx];
                float4 k0 = kb4[j], k1 = kb4[16 + j], k2 = kb4[32 + j],
                       k3 = kb4[48 + j], kw = kb4[64 + j];
                d0 += mv.x * k0.x + mv.y * k0.y + mv.z * k0.z + mv.w * k0.w;
                d1 += mv.x * k1.x + mv.y * k1.y + mv.z * k1.z + mv.w * k1.w;
                d2 += mv.x * k2.x + mv.y * k2.y + mv.z * k2.z + mv.w * k2.w;
                d3 += mv.x * k3.x + mv.y * k3.y + mv.z * k3.z + mv.w * k3.w;
                d4 += mv.x * kw.x + mv.y * kw.y + mv.z * kw.z + mv.w * kw.w;
            }
            d0 += __shfl_xor(d0, 1); d1 += __shfl_xor(d1, 1); d2 += __shfl_xor(d2, 1);
            d3 += __shfl_xor(d3, 1); d4 += __shfl_xor(d4, 1);
            if (half == 0) {
                sc->u[n] = d0; sc->u[512 + n] = d1; sc->u[1024 + n] = d2;
                sc->u[1536 + n] = d3; sc->u[2048 + n] = d4;
            }
        }
        __syncthreads();                                   // B3

        // ---- P4: waves 0-4 addressing; waves 5-8 xpart(t+1); wave 9 zeroes r ----
        if (wave < NHEAD) {
            const int h = wave;
            const float* sb = sc->instr + 448 + h * 6;
            float kv = sc->instr[h * 64 + lane];
            float sq = kv * kv;
#pragma unroll
            for (int off = 32; off; off >>= 1) sq += __shfl_xor(sq, off);
            float kn = sqrtf(sq);
            float beta = __expf(sb[0]);
            float g = 1.f / (1.f + __expf(-sb[1]));
            float v0 = sb[2], v1 = sb[3], v2 = sb[4];
            float mx3 = fmaxf(v0, fmaxf(v1, v2));
            float e0 = __expf(v0 - mx3), e1 = __expf(v1 - mx3), e2 = __expf(v2 - mx3);
            float inv3 = 1.f / (e0 + e1 + e2);
            float s0 = e0 * inv3, s1 = e1 * inv3, s2 = e2 * inv3;
            float tv = sb[5];
            float tp = fmaxf(tv, 0.f)
                     + LN2 * __builtin_amdgcn_logf(1.f + __builtin_amdgcn_exp2f(-fabsf(tv) * L2E))
                     + 1.f;

            float uu[8];
#pragma unroll
            for (int j = 0; j < 8; ++j) {
                int slot = j * 64 + lane;
                float d = sc->u[h * NSLOT + slot];
                uu[j] = beta * d / (kn * sc->mn[slot] + 1e-8f);
            }
            float m = uu[0];
#pragma unroll
            for (int j = 1; j < 8; ++j) m = fmaxf(m, uu[j]);
#pragma unroll
            for (int off = 32; off; off >>= 1) m = fmaxf(m, __shfl_xor(m, off));
            float ev[8]; float Z = 0.f;
#pragma unroll
            for (int j = 0; j < 8; ++j) { ev[j] = __expf(uu[j] - m); Z += ev[j]; }
#pragma unroll
            for (int off = 32; off; off >>= 1) Z += __shfl_xor(Z, off);
            float invZ = 1.f / Z;
            float wg[8];
#pragma unroll
            for (int j = 0; j < 8; ++j) {
                int n = j * 64 + lane;
                float wp = (h < 4) ? sc->wread4[n * 4 + h] : sc->wwrite[n];
                wg[j] = g * ev[j] * invZ + (1.f - g) * wp;
            }
            int lm = (lane + 63) & 63, lp = (lane + 1) & 63;
            float rm[8], rp[8], b63[8], b0[8];
#pragma unroll
            for (int j = 0; j < 8; ++j) {
                rm[j]  = __shfl(wg[j], lm);
                rp[j]  = __shfl(wg[j], lp);
                b63[j] = __shfl(wg[j], 63);
                b0[j]  = __shfl(wg[j], 0);
            }
            if (lane == 0) {
#pragma unroll
                for (int j = 0; j < 8; ++j) rm[j] = b63[(j + 7) & 7];
            }
            if (lane == 63) {
#pragma unroll
                for (int j = 0; j < 8; ++j) rp[j] = b0[(j + 1) & 7];
            }
            float wt[8]; float S = 0.f;
#pragma unroll
            for (int j = 0; j < 8; ++j) {
                float wsh = s0 * rp[j] + s1 * wg[j] + s2 * rm[j];
                wt[j] = __builtin_amdgcn_exp2f(tp * __builtin_amdgcn_logf(wsh));
                S += wt[j];
            }
#pragma unroll
            for (int off = 32; off; off >>= 1) S += __shfl_xor(S, off);
            float invS = 1.f / (S + 1e-8f);
            if (h < 4) {
#pragma unroll
                for (int j = 0; j < 8; ++j)
                    sc->wread4[(j * 64 + lane) * 4 + h] = wt[j] * invS;
            } else {
#pragma unroll
                for (int j = 0; j < 8; ++j)
                    sc->wwrite[j * 64 + lane] = wt[j] * invS;
            }
        } else if (wave < 9) {
            int col = tid - 320;                            // 0..255
            const uint4* wq = (const uint4*)wctb + col;
            const float4* xa = (const float4*)(sc->ctrl + (((t + 1) & 1) << 7));
            float acc = bcv4;
#pragma unroll
            for (int cc = 0; cc < 16; ++cc) {
                uint4 wv = wq[cc * 256];
                BFU_DOT(wv, xa[2 * cc], xa[2 * cc + 1], acc);
            }
            sc->xpart[col] = acc;
        } else if (wave == 9) {
            ((float4*)(sc->ctrl + 256))[lane] = make_float4(0.f, 0.f, 0.f, 0.f);
        }
        __syncthreads();                                   // B4

        // ---- P5: erase/add + row norm, 2 threads/row ----
        {
            int n = tid >> 1, half = tid & 1, nx = n & 15;
            float4* m4 = (float4*)sc->mem + n * 16;
            const float4* e4 = (const float4*)(sc->instr + 320);
            const float4* a4 = (const float4*)(sc->instr + 384);
            float wv = sc->wwrite[n];
            float nsq = 0.f;
#pragma unroll
            for (int jj = 0; jj < 8; ++jj) {
                int j = half * 8 + jj;
                float4 mv = m4[j ^ nx];
                float4 ev = e4[j], av = a4[j];
                mv.x = mv.x * (1.f - wv * ev.x) + wv * av.x;
                mv.y = mv.y * (1.f - wv * ev.y) + wv * av.y;
                mv.z = mv.z * (1.f - wv * ev.z) + wv * av.z;
                mv.w = mv.w * (1.f - wv * ev.w) + wv * av.w;
                nsq += mv.x * mv.x + mv.y * mv.y + mv.z * mv.z + mv.w * mv.w;
                m4[j ^ nx] = mv;
            }
            nsq += __shfl_xor(nsq, 1);
            if (half == 0) sc->mn[n] = sqrtf(nsq);
        }
        __syncthreads();                                   // B5

        // ---- P6: read pass, 16 waves x 32 rows; ds_add into ctrl r-region ----
        {
            int rg = lane >> 4, j = lane & 15;
            int base = wave * 32;
            float4 ac0 = make_float4(0.f,0.f,0.f,0.f), ac1 = ac0, ac2 = ac0, ac3 = ac0;
#pragma unroll
            for (int i = 0; i < 8; ++i) {
                int n = base + 4 * i + rg;
                float4 mv = ((const float4*)sc->mem)[n * 16 + (j ^ (n & 15))];
                float4 wv = ((const float4*)sc->wread4)[n];
                ac0.x += wv.x * mv.x; ac0.y += wv.x * mv.y; ac0.z += wv.x * mv.z; ac0.w += wv.x * mv.w;
                ac1.x += wv.y * mv.x; ac1.y += wv.y * mv.y; ac1.z += wv.y * mv.z; ac1.w += wv.y * mv.w;
                ac2.x += wv.z * mv.x; ac2.y += wv.z * mv.y; ac2.z += wv.z * mv.z; ac2.w += wv.z * mv.w;
                ac3.x += wv.w * mv.x; ac3.y += wv.w * mv.y; ac3.z += wv.w * mv.z; ac3.w += wv.w * mv.w;
            }
            float af[16] = { ac0.x, ac0.y, ac0.z, ac0.w, ac1.x, ac1.y, ac1.z, ac1.w,
                             ac2.x, ac2.y, ac2.z, ac2.w, ac3.x, ac3.y, ac3.z, ac3.w };
#pragma unroll
            for (int q = 0; q < 16; ++q) {
                af[q] += __shfl_xor(af[q], 16);
                af[q] += __shfl_xor(af[q], 32);
            }
            float sx = (rg == 0) ? af[0] : (rg == 1) ? af[4] : (rg == 2) ? af[8]  : af[12];
            float sy = (rg == 0) ? af[1] : (rg == 1) ? af[5] : (rg == 2) ? af[9]  : af[13];
            float sz = (rg == 0) ? af[2] : (rg == 1) ? af[6] : (rg == 2) ? af[10] : af[14];
            float sw = (rg == 0) ? af[3] : (rg == 1) ? af[7] : (rg == 2) ? af[11] : af[15];
            float* rdst = sc->ctrl + 256 + rg * 64 + j * 4;
            atomicAdd(&rdst[0], sx);
            atomicAdd(&rdst[1], sy);
            atomicAdd(&rdst[2], sz);
            atomicAdd(&rdst[3], sw);
        }
        __syncthreads();                                   // B6
    }
}

extern "C" void kernel_launch(void* const* d_in, const int* in_sizes, int n_in,
                              void* d_out, int out_size, void* d_ws, size_t ws_size,
                              hipStream_t stream) {
    const float* x  = (const float*)d_in[0];
    const float* Wc = (const float*)d_in[1];
    const float* bc = (const float*)d_in[2];
    const float* Hk = (const float*)d_in[3];
    const float* hb = (const float*)d_in[4];
    float* out = (float*)d_out;

    unsigned short* wctb = (unsigned short*)d_ws;
    unsigned short* hkb  = (unsigned short*)((char*)d_ws + HKB_OFF);

    static_assert(sizeof(SMem) <= 163840, "LDS overflow");
    (void)hipFuncSetAttribute((const void*)ntm_kernel,
                              hipFuncAttributeMaxDynamicSharedMemorySize,
                              (int)sizeof(SMem));

    hipLaunchKernelGGL(pack_kernel, dim3(478), dim3(256), 0, stream, Wc, Hk, wctb, hkb);
    hipLaunchKernelGGL(ntm_kernel, dim3(BB), dim3(NT), sizeof(SMem), stream,
                       x, bc, hb, wctb, hkb, out);
}